// Round 1
// 133.646 us; speedup vs baseline: 1.3015x; 1.3015x over previous
//
#include <hip/hip_runtime.h>
#include <math.h>

#define LN_EPS 1e-3f

typedef __attribute__((ext_vector_type(8))) short short8;
typedef __attribute__((ext_vector_type(4))) float floatx4;

__device__ __forceinline__ float silu_f(float x) { return x / (1.f + expf(-x)); }

__device__ __forceinline__ int mism1(float a, float s) {
    unsigned ua = __float_as_uint(a);
    unsigned ub = __float_as_uint(a + s);
    return (int)((ua ^ ub) >> 31);
}

__device__ __forceinline__ short f2bf(float f) {
    unsigned u = __float_as_uint(f);
    unsigned r = (u + 0x7FFFu + ((u >> 16) & 1u)) >> 16;
    return (short)r;
}

// ---------------- Kernel 0: swizzle conv1 + conv2 weights into B-fragment bf16
// w1s[kc(8)][ks(10)][nt(8)][lane(64)][j(8)]  (327,680)
// w2s[ks(12)][nt(64)][lane(64)][j(8)]        (393,216)
__global__ __launch_bounds__(256) void k_prep(
    const float* __restrict__ w1,   // (5,512,128)
    const float* __restrict__ w2,   // (3,128,1024)
    short* __restrict__ w1s,
    short* __restrict__ w2s)
{
    int tid = blockIdx.x * 256 + threadIdx.x;
    if (tid < 327680) {
        int j    = tid & 7;
        int lane = (tid >> 3) & 63;
        int nt   = (tid >> 9) & 7;
        int ks   = (tid >> 12) % 10;
        int kc   = tid / 40960;
        int kw = ks >> 1;
        int ci = kc * 64 + (ks & 1) * 32 + ((lane >> 4) & 3) * 8 + j;
        int n  = nt * 16 + (lane & 15);
        w1s[tid] = f2bf(w1[((size_t)(kw * 512 + ci)) * 128 + n]);
    } else {
        int t = tid - 327680;
        if (t < 393216) {
            int j    = t & 7;
            int lane = (t >> 3) & 63;
            int nt   = (t >> 9) & 63;
            int ks   = t >> 15;                 // 0..11
            int k  = ks * 32 + ((lane >> 4) & 3) * 8 + j;   // 0..383
            int kw = k >> 7;
            int ci = k & 127;
            int n  = nt * 16 + (lane & 15);
            w2s[t] = f2bf(w2[((size_t)(kw * 128 + ci)) * 1024 + n]);
        }
    }
}

// ---------------- Kernel 1: conv1 MFMA + bias + LN1(128) + SiLU -> h1 bf16
// grid = 200 blocks (16 pos each), 512 threads (8 waves, 1 n-tile each).
// Whole 50x512 input tile staged to LDS ONCE (52KB) -> single barrier,
// then an uninterrupted 80-MFMA pipeline per wave.
__global__ __launch_bounds__(512) void k_conv1m(
    const float* __restrict__ values,   // (4,1920,512)
    const float* __restrict__ symbols,  // (1920,512)
    const short* __restrict__ w1s,
    const float* __restrict__ b1,
    const float* __restrict__ g1,
    const float* __restrict__ bt1,
    short* __restrict__ h1)             // (3200,128) bf16
{
    int mt  = blockIdx.x;               // 0..199
    int seq = mt / 40;
    int tl  = mt % 40;
    const float* x = (seq < 4) ? (values + (size_t)seq * 1920 * 512) : symbols;
    int p0 = 48 * tl - 1;

    __shared__ short xs[50 * 520];      // 50 rows x 512 ci, +8 pad
    __shared__ float red[8][4][4][2];

    int tid  = threadIdx.x;
    int lane = tid & 63, w = tid >> 6;  // 8 waves
    int quad = lane >> 4, mrow = lane & 15;

    // stage ALL 50x512 floats as bf16 (6400 float4 loads over 512 threads)
    for (int idx = tid; idx < 6400; idx += 512) {
        int r = idx >> 7, g = idx & 127;
        int gp = p0 + r;
        float4 v = make_float4(0.f, 0.f, 0.f, 0.f);
        if (gp >= 0 && gp < 1920)
            v = *(const float4*)(x + (size_t)gp * 512 + 4 * g);
        short4 pk;
        pk.x = f2bf(v.x); pk.y = f2bf(v.y); pk.z = f2bf(v.z); pk.w = f2bf(v.w);
        *(short4*)(xs + r * 520 + 4 * g) = pk;
    }
    __syncthreads();

    floatx4 acc = (floatx4){0.f, 0.f, 0.f, 0.f};
    for (int kc = 0; kc < 8; kc++) {
        #pragma unroll
        for (int ks = 0; ks < 10; ks++) {
            int kw  = ks >> 1;
            int ci  = kc * 64 + (ks & 1) * 32 + quad * 8;
            short8 a = *(const short8*)(xs + (3 * mrow + kw) * 520 + ci);
            short8 b = *(const short8*)(w1s +
                (((size_t)(kc * 10 + ks) * 8 + w) * 64 + lane) * 8);
            acc = __builtin_amdgcn_mfma_f32_16x16x32_bf16(a, b, acc, 0, 0, 0);
        }
    }

    int co = w * 16 + mrow;
    float b1v = b1[co], g1v = g1[co], btv = bt1[co];

    float s1[4], s2[4];
    #pragma unroll
    for (int r = 0; r < 4; r++) {
        float v = acc[r] + b1v;
        acc[r] = v;
        s1[r] = v; s2[r] = v * v;
    }
    #pragma unroll
    for (int m = 8; m >= 1; m >>= 1) {
        #pragma unroll
        for (int r = 0; r < 4; r++) {
            s1[r] += __shfl_xor(s1[r], m, 64);
            s2[r] += __shfl_xor(s2[r], m, 64);
        }
    }
    if (mrow == 0) {
        #pragma unroll
        for (int r = 0; r < 4; r++) { red[w][quad][r][0] = s1[r]; red[w][quad][r][1] = s2[r]; }
    }
    __syncthreads();

    #pragma unroll
    for (int r = 0; r < 4; r++) {
        float S1 = 0.f, S2 = 0.f;
        #pragma unroll
        for (int ww = 0; ww < 8; ww++) { S1 += red[ww][quad][r][0]; S2 += red[ww][quad][r][1]; }
        float mean = S1 * (1.f / 128.f);
        float var  = S2 * (1.f / 128.f) - mean * mean;
        float rs   = rsqrtf(var + LN_EPS);
        int row = seq * 640 + tl * 16 + quad * 4 + r;
        float o = silu_f((acc[r] - mean) * rs * g1v + btv);
        h1[(size_t)row * 128 + co] = f2bf(o);
    }
}

// ---------------- Kernel 2: conv2 MFMA (16 pos x 1024 co) + LN2 + SiLU -> vp/sp
// grid = 40 blocks, 1024 threads (16 waves, 4 n-tiles each) -> 50% occupancy
// on the 40 active CUs instead of 12.5%.
__global__ __launch_bounds__(1024) void k_conv2m(
    const short* __restrict__ h1,    // (3200,128) bf16
    const short* __restrict__ w2s,
    const float* __restrict__ b2,
    const float* __restrict__ g2,
    const float* __restrict__ bt2,
    float* __restrict__ vp,          // (512,1024)
    float* __restrict__ sp)          // (128,1024)
{
    int blk  = blockIdx.x;           // 0..39
    int pos0 = blk * 16;
    int seq  = pos0 >> 7;
    int lcl0 = pos0 & 127;
    int row0 = seq * 640 + 5 * lcl0;

    __shared__ short xa[78 * 136];
    __shared__ float red[16][4][4][2];

    int tid = threadIdx.x;
    int lane = tid & 63, w = tid >> 6;   // 16 waves
    int quad = lane >> 4, mrow = lane & 15;

    for (int idx = tid; idx < 78 * 16; idx += 1024) {
        int r = idx >> 4, g = idx & 15;
        *(short8*)(xa + r * 136 + g * 8) =
            *(const short8*)(h1 + (size_t)(row0 + r) * 128 + g * 8);
    }
    __syncthreads();

    floatx4 acc[4];
    #pragma unroll
    for (int nt = 0; nt < 4; nt++) acc[nt] = (floatx4){0.f, 0.f, 0.f, 0.f};

    #pragma unroll
    for (int ks = 0; ks < 12; ks++) {
        int kw  = ks >> 2;
        int ci0 = (ks & 3) * 32;
        short8 a = *(const short8*)(xa + (5 * mrow + kw) * 136 + ci0 + quad * 8);
        #pragma unroll
        for (int nt = 0; nt < 4; nt++) {
            short8 b = *(const short8*)(w2s +
                (((size_t)ks * 64 + w * 4 + nt) * 64 + lane) * 8);
            acc[nt] = __builtin_amdgcn_mfma_f32_16x16x32_bf16(a, b, acc[nt], 0, 0, 0);
        }
    }

    float b2v[4], g2v[4], btv[4];
    #pragma unroll
    for (int nt = 0; nt < 4; nt++) {
        int co = w * 64 + nt * 16 + mrow;
        b2v[nt] = b2[co]; g2v[nt] = g2[co]; btv[nt] = bt2[co];
    }

    float s1[4] = {0.f, 0.f, 0.f, 0.f}, s2[4] = {0.f, 0.f, 0.f, 0.f};
    #pragma unroll
    for (int nt = 0; nt < 4; nt++)
        #pragma unroll
        for (int r = 0; r < 4; r++) {
            float v = acc[nt][r] + b2v[nt];
            acc[nt][r] = v;
            s1[r] += v; s2[r] += v * v;
        }
    #pragma unroll
    for (int m = 8; m >= 1; m >>= 1) {
        #pragma unroll
        for (int r = 0; r < 4; r++) {
            s1[r] += __shfl_xor(s1[r], m, 64);
            s2[r] += __shfl_xor(s2[r], m, 64);
        }
    }
    if (mrow == 0) {
        #pragma unroll
        for (int r = 0; r < 4; r++) { red[w][quad][r][0] = s1[r]; red[w][quad][r][1] = s2[r]; }
    }
    __syncthreads();

    float mean[4], rs[4];
    #pragma unroll
    for (int r = 0; r < 4; r++) {
        float S1 = 0.f, S2 = 0.f;
        #pragma unroll
        for (int ww = 0; ww < 16; ww++) { S1 += red[ww][quad][r][0]; S2 += red[ww][quad][r][1]; }
        mean[r] = S1 * (1.f / 1024.f);
        float var = S2 * (1.f / 1024.f) - mean[r] * mean[r];
        rs[r] = rsqrtf(var + LN_EPS);
    }

    float* obase = (pos0 < 512) ? (vp + (size_t)pos0 * 1024)
                                : (sp + (size_t)(pos0 - 512) * 1024);
    #pragma unroll
    for (int nt = 0; nt < 4; nt++) {
        int co = w * 64 + nt * 16 + mrow;
        #pragma unroll
        for (int r = 0; r < 4; r++) {
            float o = silu_f((acc[nt][r] - mean[r]) * rs[r] * g2v[nt] + btv[nt]);
            obase[((size_t)(quad * 4 + r)) * 1024 + co] = o;
        }
    }
}

// ---------------- Kernel 3: fused attention (counts + softmax + einsum + SiLU)
// grid = 4b * 64 jpair = 256 blocks, 1024 threads (16 waves -> 50% occupancy).
// sp rows staged to LDS once; phase C shares each vp load across both j's
// with a 4-way i-split + LDS combine.
__global__ __launch_bounds__(1024) void k_attn(
    const float* __restrict__ vp,   // (512,1024)
    const float* __restrict__ sp,   // (128,1024)
    float* __restrict__ O)          // (4,128,1024)
{
    int b  = blockIdx.x >> 6;
    int j0 = (blockIdx.x & 63) * 2;
    int tid = threadIdx.x, lane = tid & 63, wv = tid >> 6;

    __shared__ float  ss[2][1024];      // 8KB  : the two symbol rows
    __shared__ int    cc[8][128][2];    // 8KB  : partial mismatch counts
    __shared__ float  sc0[128], sc1[128];
    __shared__ float  reds[2][16];
    __shared__ float4 redc[4][2][256];  // 32KB : phase-C partials

    // stage the two sp rows (512 float4 over first 512 threads)
    if (tid < 512) {
        int jj = tid >> 8, g = tid & 255;
        *(float4*)(&ss[jj][4 * g]) = *(const float4*)(sp + (size_t)(j0 + jj) * 1024 + 4 * g);
    }
    __syncthreads();

    // phase A: mismatch counts; thread = (i = tid>>3, sub = tid&7 covers 128 d)
    {
        int i = tid >> 3, sub = tid & 7;
        const float* vrow = vp + ((size_t)(b * 128 + i)) * 1024;
        int m0 = 0, m1 = 0;
        #pragma unroll 8
        for (int k = 0; k < 32; k++) {
            int q = 4 * (sub + 8 * k);           // lane-contiguous float4 column
            float4 v  = *(const float4*)(vrow + q);
            float4 s0 = *(const float4*)(&ss[0][q]);
            float4 s1 = *(const float4*)(&ss[1][q]);
            m0 += mism1(v.x, s0.x) + mism1(v.y, s0.y) + mism1(v.z, s0.z) + mism1(v.w, s0.w);
            m1 += mism1(v.x, s1.x) + mism1(v.y, s1.y) + mism1(v.z, s1.z) + mism1(v.w, s1.w);
        }
        cc[sub][i][0] = m0;
        cc[sub][i][1] = m1;
    }
    __syncthreads();

    // phase B: softmax over i=128 for both j's (S in [-1,1], no max needed)
    float e0 = 0.f, e1 = 0.f;
    if (tid < 128) {
        int c0 = 0, c1 = 0;
        #pragma unroll
        for (int s = 0; s < 8; s++) { c0 += cc[s][tid][0]; c1 += cc[s][tid][1]; }
        e0 = expf(1.f - (float)c0 * (2.f / 1024.f));
        e1 = expf(1.f - (float)c1 * (2.f / 1024.f));
    }
    float t0 = e0, t1 = e1;
    #pragma unroll
    for (int m = 32; m >= 1; m >>= 1) {
        t0 += __shfl_xor(t0, m, 64);
        t1 += __shfl_xor(t1, m, 64);
    }
    if (lane == 0) { reds[0][wv] = t0; reds[1][wv] = t1; }
    __syncthreads();
    if (tid < 128) {
        float tot0 = 0.f, tot1 = 0.f;
        #pragma unroll
        for (int ww = 0; ww < 16; ww++) { tot0 += reds[0][ww]; tot1 += reds[1][ww]; }
        sc0[tid] = e0 / tot0;
        sc1[tid] = e1 / tot1;
    }
    __syncthreads();

    // phase C: einsum, v loaded once serves BOTH j's; 4-way i-split
    {
        int dloc = tid & 255, iq = tid >> 8;
        int dd = 4 * dloc;
        const float* vpb = vp + (size_t)b * 131072 + (size_t)iq * 32 * 1024;
        float4 a0 = make_float4(0.f, 0.f, 0.f, 0.f);
        float4 a1 = make_float4(0.f, 0.f, 0.f, 0.f);
        #pragma unroll 8
        for (int k = 0; k < 32; k++) {
            float4 v = *(const float4*)(vpb + (size_t)k * 1024 + dd);
            float f0 = sc0[iq * 32 + k];
            float f1 = sc1[iq * 32 + k];
            a0.x += f0 * v.x; a0.y += f0 * v.y; a0.z += f0 * v.z; a0.w += f0 * v.w;
            a1.x += f1 * v.x; a1.y += f1 * v.y; a1.z += f1 * v.z; a1.w += f1 * v.w;
        }
        redc[iq][0][dloc] = a0;
        redc[iq][1][dloc] = a1;
    }
    __syncthreads();
    if (tid < 512) {
        int jj = tid >> 8, dloc = tid & 255;
        int dd = 4 * dloc;
        float4 r0 = redc[0][jj][dloc], r1 = redc[1][jj][dloc];
        float4 r2 = redc[2][jj][dloc], r3 = redc[3][jj][dloc];
        float4 ao;
        ao.x = r0.x + r1.x + r2.x + r3.x;
        ao.y = r0.y + r1.y + r2.y + r3.y;
        ao.z = r0.z + r1.z + r2.z + r3.z;
        ao.w = r0.w + r1.w + r2.w + r3.w;
        float4 o;
        o.x = silu_f(ao.x * ss[jj][dd + 0]);
        o.y = silu_f(ao.y * ss[jj][dd + 1]);
        o.z = silu_f(ao.z * ss[jj][dd + 2]);
        o.w = silu_f(ao.w * ss[jj][dd + 3]);
        *(float4*)(O + ((size_t)(b * 128 + j0 + jj)) * 1024 + dd) = o;
    }
}

extern "C" void kernel_launch(void* const* d_in, const int* in_sizes, int n_in,
                              void* d_out, int out_size, void* d_ws, size_t ws_size,
                              hipStream_t stream) {
    const float* values  = (const float*)d_in[0];
    const float* symbols = (const float*)d_in[1];
    const float* conv1_w = (const float*)d_in[2];
    const float* conv1_b = (const float*)d_in[3];
    const float* ln1_g   = (const float*)d_in[4];
    const float* ln1_b   = (const float*)d_in[5];
    const float* conv2_w = (const float*)d_in[6];
    const float* conv2_b = (const float*)d_in[7];
    const float* ln2_g   = (const float*)d_in[8];
    const float* ln2_b   = (const float*)d_in[9];

    float* out = (float*)d_out;
    float* O   = out;                       // (4,128,1024)
    float* vp  = out + 4 * 128 * 1024;      // (4,128,1024)

    float* sp  = (float*)d_ws;              // (128,1024) f32
    short* h1  = (short*)(sp + 128 * 1024); // (3200,128) bf16
    short* w1s = h1 + 3200 * 128;           // 327,680
    short* w2s = w1s + 327680;              // 393,216

    k_prep<<<2816, 256, 0, stream>>>(conv1_w, conv2_w, w1s, w2s);
    k_conv1m<<<200, 512, 0, stream>>>(values, symbols, w1s,
                                      conv1_b, ln1_g, ln1_b, h1);
    k_conv2m<<<40, 1024, 0, stream>>>(h1, w2s, conv2_b, ln2_g, ln2_b, vp, sp);
    k_attn<<<256, 1024, 0, stream>>>(vp, sp, O);
}

// Round 2
// 132.151 us; speedup vs baseline: 1.3162x; 1.0113x over previous
//
#include <hip/hip_runtime.h>
#include <math.h>

#define LN_EPS 1e-3f

typedef __attribute__((ext_vector_type(8))) short short8;
typedef __attribute__((ext_vector_type(4))) float floatx4;

__device__ __forceinline__ float silu_f(float x) { return x / (1.f + expf(-x)); }

__device__ __forceinline__ int mism1(float a, float s) {
    unsigned ua = __float_as_uint(a);
    unsigned ub = __float_as_uint(a + s);
    return (int)((ua ^ ub) >> 31);
}

__device__ __forceinline__ short f2bf(float f) {
    unsigned u = __float_as_uint(f);
    unsigned r = (u + 0x7FFFu + ((u >> 16) & 1u)) >> 16;
    return (short)r;
}

// ---------------- Kernel 0: swizzle conv1 + conv2 weights into B-fragment bf16
// w1s[kc(8)][ks(10)][nt(8)][lane(64)][j(8)]  (327,680)
// w2s[ks(12)][nt(64)][lane(64)][j(8)]        (393,216)
__global__ __launch_bounds__(256) void k_prep(
    const float* __restrict__ w1,   // (5,512,128)
    const float* __restrict__ w2,   // (3,128,1024)
    short* __restrict__ w1s,
    short* __restrict__ w2s)
{
    int tid = blockIdx.x * 256 + threadIdx.x;
    if (tid < 327680) {
        int j    = tid & 7;
        int lane = (tid >> 3) & 63;
        int nt   = (tid >> 9) & 7;
        int ks   = (tid >> 12) % 10;
        int kc   = tid / 40960;
        int kw = ks >> 1;
        int ci = kc * 64 + (ks & 1) * 32 + ((lane >> 4) & 3) * 8 + j;
        int n  = nt * 16 + (lane & 15);
        w1s[tid] = f2bf(w1[((size_t)(kw * 512 + ci)) * 128 + n]);
    } else {
        int t = tid - 327680;
        if (t < 393216) {
            int j    = t & 7;
            int lane = (t >> 3) & 63;
            int nt   = (t >> 9) & 63;
            int ks   = t >> 15;                 // 0..11
            int k  = ks * 32 + ((lane >> 4) & 3) * 8 + j;   // 0..383
            int kw = k >> 7;
            int ci = k & 127;
            int n  = nt * 16 + (lane & 15);
            w2s[t] = f2bf(w2[((size_t)(kw * 128 + ci)) * 1024 + n]);
        }
    }
}

// ---------------- Kernel 1: conv1 MFMA + bias + LN1(128) + SiLU -> h1 bf16
// grid = 200 blocks (16 pos each), 512 threads (8 waves, 1 n-tile each).
__global__ __launch_bounds__(512) void k_conv1m(
    const float* __restrict__ values,   // (4,1920,512)
    const float* __restrict__ symbols,  // (1920,512)
    const short* __restrict__ w1s,
    const float* __restrict__ b1,
    const float* __restrict__ g1,
    const float* __restrict__ bt1,
    short* __restrict__ h1)             // (3200,128) bf16
{
    int mt  = blockIdx.x;               // 0..199
    int seq = mt / 40;
    int tl  = mt % 40;
    const float* x = (seq < 4) ? (values + (size_t)seq * 1920 * 512) : symbols;
    int p0 = 48 * tl - 1;

    __shared__ short xs[50 * 520];      // 50 rows x 512 ci, +8 pad
    __shared__ float red[8][4][4][2];

    int tid  = threadIdx.x;
    int lane = tid & 63, w = tid >> 6;  // 8 waves
    int quad = lane >> 4, mrow = lane & 15;

    for (int idx = tid; idx < 6400; idx += 512) {
        int r = idx >> 7, g = idx & 127;
        int gp = p0 + r;
        float4 v = make_float4(0.f, 0.f, 0.f, 0.f);
        if (gp >= 0 && gp < 1920)
            v = *(const float4*)(x + (size_t)gp * 512 + 4 * g);
        short4 pk;
        pk.x = f2bf(v.x); pk.y = f2bf(v.y); pk.z = f2bf(v.z); pk.w = f2bf(v.w);
        *(short4*)(xs + r * 520 + 4 * g) = pk;
    }
    __syncthreads();

    floatx4 acc = (floatx4){0.f, 0.f, 0.f, 0.f};
    for (int kc = 0; kc < 8; kc++) {
        #pragma unroll
        for (int ks = 0; ks < 10; ks++) {
            int kw  = ks >> 1;
            int ci  = kc * 64 + (ks & 1) * 32 + quad * 8;
            short8 a = *(const short8*)(xs + (3 * mrow + kw) * 520 + ci);
            short8 b = *(const short8*)(w1s +
                (((size_t)(kc * 10 + ks) * 8 + w) * 64 + lane) * 8);
            acc = __builtin_amdgcn_mfma_f32_16x16x32_bf16(a, b, acc, 0, 0, 0);
        }
    }

    int co = w * 16 + mrow;
    float b1v = b1[co], g1v = g1[co], btv = bt1[co];

    float s1[4], s2[4];
    #pragma unroll
    for (int r = 0; r < 4; r++) {
        float v = acc[r] + b1v;
        acc[r] = v;
        s1[r] = v; s2[r] = v * v;
    }
    #pragma unroll
    for (int m = 8; m >= 1; m >>= 1) {
        #pragma unroll
        for (int r = 0; r < 4; r++) {
            s1[r] += __shfl_xor(s1[r], m, 64);
            s2[r] += __shfl_xor(s2[r], m, 64);
        }
    }
    if (mrow == 0) {
        #pragma unroll
        for (int r = 0; r < 4; r++) { red[w][quad][r][0] = s1[r]; red[w][quad][r][1] = s2[r]; }
    }
    __syncthreads();

    #pragma unroll
    for (int r = 0; r < 4; r++) {
        float S1 = 0.f, S2 = 0.f;
        #pragma unroll
        for (int ww = 0; ww < 8; ww++) { S1 += red[ww][quad][r][0]; S2 += red[ww][quad][r][1]; }
        float mean = S1 * (1.f / 128.f);
        float var  = S2 * (1.f / 128.f) - mean * mean;
        float rs   = rsqrtf(var + LN_EPS);
        int row = seq * 640 + tl * 16 + quad * 4 + r;
        float o = silu_f((acc[r] - mean) * rs * g1v + btv);
        h1[(size_t)row * 128 + co] = f2bf(o);
    }
}

// ---------------- Kernel 2: conv2 MFMA (16 pos x 1024 co) + LN2 + SiLU -> vp/sp
// grid = 40 blocks, 1024 threads (16 waves, 4 n-tiles each).
__global__ __launch_bounds__(1024) void k_conv2m(
    const short* __restrict__ h1,    // (3200,128) bf16
    const short* __restrict__ w2s,
    const float* __restrict__ b2,
    const float* __restrict__ g2,
    const float* __restrict__ bt2,
    float* __restrict__ vp,          // (512,1024)
    float* __restrict__ sp)          // (128,1024)
{
    int blk  = blockIdx.x;           // 0..39
    int pos0 = blk * 16;
    int seq  = pos0 >> 7;
    int lcl0 = pos0 & 127;
    int row0 = seq * 640 + 5 * lcl0;

    __shared__ short xa[78 * 136];
    __shared__ float red[16][4][4][2];

    int tid = threadIdx.x;
    int lane = tid & 63, w = tid >> 6;   // 16 waves
    int quad = lane >> 4, mrow = lane & 15;

    for (int idx = tid; idx < 78 * 16; idx += 1024) {
        int r = idx >> 4, g = idx & 15;
        *(short8*)(xa + r * 136 + g * 8) =
            *(const short8*)(h1 + (size_t)(row0 + r) * 128 + g * 8);
    }
    __syncthreads();

    floatx4 acc[4];
    #pragma unroll
    for (int nt = 0; nt < 4; nt++) acc[nt] = (floatx4){0.f, 0.f, 0.f, 0.f};

    #pragma unroll
    for (int ks = 0; ks < 12; ks++) {
        int kw  = ks >> 2;
        int ci0 = (ks & 3) * 32;
        short8 a = *(const short8*)(xa + (5 * mrow + kw) * 136 + ci0 + quad * 8);
        #pragma unroll
        for (int nt = 0; nt < 4; nt++) {
            short8 b = *(const short8*)(w2s +
                (((size_t)ks * 64 + w * 4 + nt) * 64 + lane) * 8);
            acc[nt] = __builtin_amdgcn_mfma_f32_16x16x32_bf16(a, b, acc[nt], 0, 0, 0);
        }
    }

    float b2v[4], g2v[4], btv[4];
    #pragma unroll
    for (int nt = 0; nt < 4; nt++) {
        int co = w * 64 + nt * 16 + mrow;
        b2v[nt] = b2[co]; g2v[nt] = g2[co]; btv[nt] = bt2[co];
    }

    float s1[4] = {0.f, 0.f, 0.f, 0.f}, s2[4] = {0.f, 0.f, 0.f, 0.f};
    #pragma unroll
    for (int nt = 0; nt < 4; nt++)
        #pragma unroll
        for (int r = 0; r < 4; r++) {
            float v = acc[nt][r] + b2v[nt];
            acc[nt][r] = v;
            s1[r] += v; s2[r] += v * v;
        }
    #pragma unroll
    for (int m = 8; m >= 1; m >>= 1) {
        #pragma unroll
        for (int r = 0; r < 4; r++) {
            s1[r] += __shfl_xor(s1[r], m, 64);
            s2[r] += __shfl_xor(s2[r], m, 64);
        }
    }
    if (mrow == 0) {
        #pragma unroll
        for (int r = 0; r < 4; r++) { red[w][quad][r][0] = s1[r]; red[w][quad][r][1] = s2[r]; }
    }
    __syncthreads();

    float mean[4], rs[4];
    #pragma unroll
    for (int r = 0; r < 4; r++) {
        float S1 = 0.f, S2 = 0.f;
        #pragma unroll
        for (int ww = 0; ww < 16; ww++) { S1 += red[ww][quad][r][0]; S2 += red[ww][quad][r][1]; }
        mean[r] = S1 * (1.f / 1024.f);
        float var = S2 * (1.f / 1024.f) - mean[r] * mean[r];
        rs[r] = rsqrtf(var + LN_EPS);
    }

    float* obase = (pos0 < 512) ? (vp + (size_t)pos0 * 1024)
                                : (sp + (size_t)(pos0 - 512) * 1024);
    #pragma unroll
    for (int nt = 0; nt < 4; nt++) {
        int co = w * 64 + nt * 16 + mrow;
        #pragma unroll
        for (int r = 0; r < 4; r++) {
            float o = silu_f((acc[nt][r] - mean[r]) * rs[r] * g2v[nt] + btv[nt]);
            obase[((size_t)(quad * 4 + r)) * 1024 + co] = o;
        }
    }
}

// ---------------- Kernel 3a: mismatch counts, d-chunked + j-amortized.
// grid = 256 blocks = (b(4) x jg(8 groups of 16 j) x dc(8 chunks of 128 d)),
// 1024 threads = (i(128) x sub(8, 16 d each)). vp slice held in registers,
// swept over 16 j from LDS -> vp read once per (b,dc) per jg (16 MB total).
// S_part[b][j][dc][i] int partial counts (exact integers).
__global__ __launch_bounds__(1024) void k_count(
    const float* __restrict__ vp,   // (512,1024)
    const float* __restrict__ sp,   // (128,1024)
    int* __restrict__ S_part)       // (4,128,8,128)
{
    int b  = blockIdx.x >> 6;
    int jg = (blockIdx.x >> 3) & 7;
    int dc = blockIdx.x & 7;
    int tid = threadIdx.x;

    // s tile: [sub(8)][16 j * 16 d], sub-stride 260 floats (bank offset +4
    // per sub -> the 8 sub-lanes of a wave hit 8 distinct bank quads).
    __shared__ float sls[8 * 260];
    __shared__ int   cnt[16][128];

    if (tid < 512) {
        int r = tid >> 5, c = tid & 31;           // j-row, float4-col
        float4 v = *(const float4*)(sp + (size_t)(jg * 16 + r) * 1024 + dc * 128 + 4 * c);
        int sub = c >> 2, off = (c & 3) * 4;
        *(float4*)&sls[sub * 260 + r * 16 + off] = v;
    }
    __syncthreads();

    int i = tid >> 3, sub = tid & 7;
    const float* vr = vp + ((size_t)(b * 128 + i)) * 1024 + dc * 128 + sub * 16;
    float4 v0 = *(const float4*)(vr + 0);
    float4 v1 = *(const float4*)(vr + 4);
    float4 v2 = *(const float4*)(vr + 8);
    float4 v3 = *(const float4*)(vr + 12);

    const float* sbase = &sls[sub * 260];
    #pragma unroll
    for (int j = 0; j < 16; j++) {
        const float4* srow = (const float4*)(sbase + j * 16);
        float4 s0 = srow[0], s1 = srow[1], s2 = srow[2], s3 = srow[3];
        int m = mism1(v0.x, s0.x) + mism1(v0.y, s0.y) + mism1(v0.z, s0.z) + mism1(v0.w, s0.w)
              + mism1(v1.x, s1.x) + mism1(v1.y, s1.y) + mism1(v1.z, s1.z) + mism1(v1.w, s1.w)
              + mism1(v2.x, s2.x) + mism1(v2.y, s2.y) + mism1(v2.z, s2.z) + mism1(v2.w, s2.w)
              + mism1(v3.x, s3.x) + mism1(v3.y, s3.y) + mism1(v3.z, s3.z) + mism1(v3.w, s3.w);
        m += __shfl_xor(m, 1, 64);
        m += __shfl_xor(m, 2, 64);
        m += __shfl_xor(m, 4, 64);
        if (sub == 0) cnt[j][i] = m;
    }
    __syncthreads();

    #pragma unroll
    for (int t = 0; t < 2; t++) {
        int idx = tid + t * 1024;
        int j = idx >> 7, ii = idx & 127;
        S_part[(((size_t)(b * 128 + jg * 16 + j)) * 8 + dc) * 128 + ii] = cnt[j][ii];
    }
}

// ---------------- Kernel 3b: softmax (from summed integer counts) + einsum + SiLU.
// grid = 256 blocks = (b(4) x jo(16 groups of 8 j) x dq(4 quarters of 256 d)),
// 1024 threads. Each vp float4 load serves 8 j's; LDS partial reduce over
// 8 i-groups of 16.
__global__ __launch_bounds__(1024) void k_sein(
    const float* __restrict__ vp,   // (512,1024)
    const float* __restrict__ sp,   // (128,1024)
    const int* __restrict__ S_part, // (4,128,8,128)
    float* __restrict__ O)          // (4,128,1024)
{
    int b  = blockIdx.x >> 6;
    int jo = (blockIdx.x >> 2) & 15;
    int dq = blockIdx.x & 3;
    int tid = threadIdx.x;

    __shared__ float  sc[8][128];
    __shared__ float4 pacc[8][8][64];   // [ig][jj][dcol], 64 KB
    __shared__ float  reds[8][2];

    // softmax for the 8 j's of this group (thread = (jj, i))
    {
        int jj = tid >> 7, ii = tid & 127;
        int j  = jo * 8 + jj;
        const int* cb = S_part + ((size_t)(b * 128 + j)) * 8 * 128 + ii;
        int c = 0;
        #pragma unroll
        for (int dcc = 0; dcc < 8; dcc++) c += cb[dcc * 128];
        float e = expf(1.f - (float)c * (2.f / 1024.f));
        float t = e;
        #pragma unroll
        for (int m = 32; m >= 1; m >>= 1) t += __shfl_xor(t, m, 64);
        if ((tid & 63) == 0) reds[jj][(tid >> 6) & 1] = t;
        __syncthreads();
        float tot = reds[jj][0] + reds[jj][1];
        sc[jj][ii] = e / tot;
    }
    __syncthreads();

    // einsum partials: 512 threads = (ig(8 groups of 16 i), dcol(64 float4))
    if (tid < 512) {
        int ig = tid >> 6, dcol = tid & 63;
        const float* vb = vp + ((size_t)(b * 128 + ig * 16)) * 1024 + dq * 256 + 4 * dcol;
        float4 acc[8];
        #pragma unroll
        for (int jj = 0; jj < 8; jj++) acc[jj] = make_float4(0.f, 0.f, 0.f, 0.f);
        #pragma unroll 4
        for (int k = 0; k < 16; k++) {
            float4 v = *(const float4*)(vb + (size_t)k * 1024);
            #pragma unroll
            for (int jj = 0; jj < 8; jj++) {
                float s = sc[jj][ig * 16 + k];    // wave-uniform -> broadcast
                acc[jj].x += s * v.x; acc[jj].y += s * v.y;
                acc[jj].z += s * v.z; acc[jj].w += s * v.w;
            }
        }
        #pragma unroll
        for (int jj = 0; jj < 8; jj++) pacc[ig][jj][dcol] = acc[jj];
    }
    __syncthreads();

    // final combine + SiLU + store: 512 threads = (jj, dcol)
    if (tid < 512) {
        int jj = tid >> 6, dcol = tid & 63;
        float4 a = pacc[0][jj][dcol];
        #pragma unroll
        for (int ig = 1; ig < 8; ig++) {
            float4 p = pacc[ig][jj][dcol];
            a.x += p.x; a.y += p.y; a.z += p.z; a.w += p.w;
        }
        int j = jo * 8 + jj;
        int d = dq * 256 + 4 * dcol;
        float4 sv = *(const float4*)(sp + (size_t)j * 1024 + d);
        float4 o;
        o.x = silu_f(a.x * sv.x);
        o.y = silu_f(a.y * sv.y);
        o.z = silu_f(a.z * sv.z);
        o.w = silu_f(a.w * sv.w);
        *(float4*)(O + ((size_t)(b * 128 + j)) * 1024 + d) = o;
    }
}

extern "C" void kernel_launch(void* const* d_in, const int* in_sizes, int n_in,
                              void* d_out, int out_size, void* d_ws, size_t ws_size,
                              hipStream_t stream) {
    const float* values  = (const float*)d_in[0];
    const float* symbols = (const float*)d_in[1];
    const float* conv1_w = (const float*)d_in[2];
    const float* conv1_b = (const float*)d_in[3];
    const float* ln1_g   = (const float*)d_in[4];
    const float* ln1_b   = (const float*)d_in[5];
    const float* conv2_w = (const float*)d_in[6];
    const float* conv2_b = (const float*)d_in[7];
    const float* ln2_g   = (const float*)d_in[8];
    const float* ln2_b   = (const float*)d_in[9];

    float* out = (float*)d_out;
    float* O   = out;                       // (4,128,1024)
    float* vp  = out + 4 * 128 * 1024;      // (4,128,1024)

    float* sp  = (float*)d_ws;              // (128,1024) f32
    short* h1  = (short*)(sp + 128 * 1024); // (3200,128) bf16
    short* w1s = h1 + 3200 * 128;           // 327,680
    short* w2s = w1s + 327680;              // 393,216
    int*   S_part = (int*)(w2s + 393216);   // (4,128,8,128) = 2 MB

    k_prep<<<2816, 256, 0, stream>>>(conv1_w, conv2_w, w1s, w2s);
    k_conv1m<<<200, 512, 0, stream>>>(values, symbols, w1s,
                                      conv1_b, ln1_g, ln1_b, h1);
    k_conv2m<<<40, 1024, 0, stream>>>(h1, w2s, conv2_b, ln2_g, ln2_b, vp, sp);
    k_count<<<256, 1024, 0, stream>>>(vp, sp, S_part);
    k_sein<<<256, 1024, 0, stream>>>(vp, sp, S_part, O);
}